// Round 1
// baseline (324.704 us; speedup 1.0000x reference)
//
#include <hip/hip_runtime.h>
#include <hip/hip_bf16.h>

#define BM 128
#define BN 128
#define BK 64
#define PAD 8
#define LDK (BK + PAD)      // 72 bf16 elems = 144 B row stride (16B-aligned)
#define MDIM 4096
#define NDIM 4096
#define KDIM 4096
#define NT (KDIM / BK)      // 64 K-iterations

typedef float f32x4 __attribute__((ext_vector_type(4)));
typedef short bf16x8 __attribute__((ext_vector_type(8)));

__device__ __forceinline__ unsigned int pack_bf16x2(float lo, float hi) {
    __hip_bfloat162 h = __float22bfloat162_rn(float2{lo, hi});
    union { __hip_bfloat162 h; unsigned int u; } c;
    c.h = h;
    return c.u;
}

__global__ __launch_bounds__(256, 2)
void fused_gemm_pool_kernel(const float* __restrict__ x,
                            const float* __restrict__ W,
                            const float* __restrict__ b,
                            float* __restrict__ out)
{
    __shared__ unsigned short As[BM][LDK];
    __shared__ unsigned short Bs[BN][LDK];

    const int tid  = threadIdx.x;
    const int lane = tid & 63;
    const int wid  = tid >> 6;      // 0..3
    const int wm   = wid >> 1;      // 0..1 (row half)
    const int wn   = wid & 1;       // 0..1 (col half)

    // XCD-aware swizzle: 1024 blocks, 8 XCDs, 1024 % 8 == 0 -> bijective
    const int bid = blockIdx.x;
    const int wg  = (bid & 7) * (1024 / 8) + (bid >> 3);
    const int bm  = wg >> 5;        // 0..31
    const int bn  = wg & 31;        // 0..31

    // staging decomposition: 256 threads -> 16 rows x 16 float4-cols per pass
    const int srow = tid >> 4;      // 0..15
    const int scol = tid & 15;      // 0..15 (float4 index within 64-float row)

    const float* xbase = x + (size_t)(bm * BM + srow) * KDIM + scol * 4;
    const float* wbase = W + (size_t)(bn * BN + srow) * KDIM + scol * 4;

    f32x4 acc[4][4];                // [m-frag][n-frag]
    #pragma unroll
    for (int i = 0; i < 4; ++i)
        #pragma unroll
        for (int j = 0; j < 4; ++j)
            acc[i][j] = (f32x4)0.0f;

    float4 ra[8], rb[8];
    #pragma unroll
    for (int p = 0; p < 8; ++p) {
        ra[p] = *(const float4*)(xbase + (size_t)(p * 16) * KDIM);
        rb[p] = *(const float4*)(wbase + (size_t)(p * 16) * KDIM);
    }

    for (int kt = 0; kt < NT; ++kt) {
        // convert staged registers -> bf16 LDS
        #pragma unroll
        for (int p = 0; p < 8; ++p) {
            const int r = srow + p * 16;
            uint2 pa, pb;
            pa.x = pack_bf16x2(ra[p].x, ra[p].y);
            pa.y = pack_bf16x2(ra[p].z, ra[p].w);
            pb.x = pack_bf16x2(rb[p].x, rb[p].y);
            pb.y = pack_bf16x2(rb[p].z, rb[p].w);
            *(uint2*)&As[r][scol * 4] = pa;
            *(uint2*)&Bs[r][scol * 4] = pb;
        }
        __syncthreads();

        // prefetch next K-tile while MFMAs run on this one
        if (kt + 1 < NT) {
            const float* xa = xbase + (size_t)(kt + 1) * BK;
            const float* wa = wbase + (size_t)(kt + 1) * BK;
            #pragma unroll
            for (int p = 0; p < 8; ++p) {
                ra[p] = *(const float4*)(xa + (size_t)(p * 16) * KDIM);
                rb[p] = *(const float4*)(wa + (size_t)(p * 16) * KDIM);
            }
        }

        // MFMA on the staged tile
        #pragma unroll
        for (int k0 = 0; k0 < 2; ++k0) {
            const int kk = k0 * 32 + (lane >> 4) * 8;
            bf16x8 af[4], bfr[4];
            #pragma unroll
            for (int mf = 0; mf < 4; ++mf)
                af[mf] = *(const bf16x8*)&As[wm * 64 + mf * 16 + (lane & 15)][kk];
            #pragma unroll
            for (int nf = 0; nf < 4; ++nf)
                bfr[nf] = *(const bf16x8*)&Bs[wn * 64 + nf * 16 + (lane & 15)][kk];
            #pragma unroll
            for (int mf = 0; mf < 4; ++mf)
                #pragma unroll
                for (int nf = 0; nf < 4; ++nf)
                    acc[mf][nf] = __builtin_amdgcn_mfma_f32_16x16x32_bf16(
                        af[mf], bfr[nf], acc[mf][nf], 0, 0, 0);
        }
        __syncthreads();
    }

    // Epilogue: bias + maxpool(K=4 along n) + sum over n + atomic row add.
    // C/D layout (16x16x32): col(n) = lane&15, row(m) = (lane>>4)*4 + reg.
    float rs[4][4];
    #pragma unroll
    for (int mf = 0; mf < 4; ++mf)
        #pragma unroll
        for (int r = 0; r < 4; ++r)
            rs[mf][r] = 0.0f;

    #pragma unroll
    for (int nf = 0; nf < 4; ++nf) {
        const float bv = b[bn * BN + wn * 64 + nf * 16 + (lane & 15)];
        #pragma unroll
        for (int mf = 0; mf < 4; ++mf) {
            #pragma unroll
            for (int r = 0; r < 4; ++r) {
                float v = acc[mf][nf][r] + bv;
                // max over the 4-column pooling group (cols live in lane bits 0..1)
                v = fmaxf(v, __shfl_xor(v, 1));
                v = fmaxf(v, __shfl_xor(v, 2));
                // sum the 4 group-maxes across the 16 columns of this fragment
                v += __shfl_xor(v, 4);
                v += __shfl_xor(v, 8);
                rs[mf][r] += v;
            }
        }
    }

    if ((lane & 15) == 0) {
        #pragma unroll
        for (int mf = 0; mf < 4; ++mf)
            #pragma unroll
            for (int r = 0; r < 4; ++r) {
                const int row = bm * BM + wm * 64 + mf * 16 + (lane >> 4) * 4 + r;
                atomicAdd(&out[row], 0.5f * rs[mf][r]);
            }
    }
}

extern "C" void kernel_launch(void* const* d_in, const int* in_sizes, int n_in,
                              void* d_out, int out_size, void* d_ws, size_t ws_size,
                              hipStream_t stream) {
    const float* x = (const float*)d_in[0];
    const float* W = (const float*)d_in[1];
    const float* b = (const float*)d_in[2];
    float* out = (float*)d_out;

    hipMemsetAsync(out, 0, (size_t)out_size * sizeof(float), stream);
    fused_gemm_pool_kernel<<<dim3(1024), dim3(256), 0, stream>>>(x, W, b, out);
}

// Round 2
// 259.803 us; speedup vs baseline: 1.2498x; 1.2498x over previous
//
#include <hip/hip_runtime.h>
#include <hip/hip_bf16.h>

#define KDIM 4096
#define NELEM (4096 * 4096)

typedef float f32x4 __attribute__((ext_vector_type(4)));
typedef short bf16x8 __attribute__((ext_vector_type(8)));

typedef const __attribute__((address_space(1))) unsigned int g_u32;
typedef __attribute__((address_space(3))) unsigned int l_u32;

__device__ __forceinline__ void gload_lds16(const void* g, void* l) {
    __builtin_amdgcn_global_load_lds((g_u32*)g, (l_u32*)l, 16, 0, 0);
}

__device__ __forceinline__ unsigned int pack_bf16x2(float lo, float hi) {
    __hip_bfloat162 h = __float22bfloat162_rn(float2{lo, hi});
    union { __hip_bfloat162 h; unsigned int u; } c;
    c.h = h;
    return c.u;
}

// ---------------- fp32 -> bf16 convert pass ----------------
__global__ __launch_bounds__(256)
void cvt_f32_bf16(const float* __restrict__ in, unsigned short* __restrict__ out, int n)
{
    const int stride = gridDim.x * blockDim.x;
    for (int i = blockIdx.x * blockDim.x + threadIdx.x; i * 8 < n; i += stride) {
        const float4 a = *(const float4*)(in + (size_t)i * 8);
        const float4 b = *(const float4*)(in + (size_t)i * 8 + 4);
        uint4 o;
        o.x = pack_bf16x2(a.x, a.y);
        o.y = pack_bf16x2(a.z, a.w);
        o.z = pack_bf16x2(b.x, b.y);
        o.w = pack_bf16x2(b.z, b.w);
        *(uint4*)(out + (size_t)i * 8) = o;
    }
}

// ---------------- main fused GEMM (m97 structure) ----------------
// C = A(bf16) * B(bf16)^T fused with bias + maxpool4 + rowsum * 0.5
__global__ __launch_bounds__(256, 2)
void gemm_bf16_pool(const unsigned short* __restrict__ A,
                    const unsigned short* __restrict__ B,
                    const float* __restrict__ bias,
                    float* __restrict__ out)
{
    __shared__ unsigned short As[128 * 64];   // linear [row][k], 128B rows
    __shared__ unsigned short Bs[128 * 64];

    const int tid  = threadIdx.x;
    const int lane = tid & 63;
    const int wid  = tid >> 6;      // 0..3
    const int wm   = wid >> 1;      // 0..1
    const int wn   = wid & 1;       // 0..1

    // XCD-aware bijective swizzle (1024 % 8 == 0)
    const int bid = blockIdx.x;
    const int wg  = (bid & 7) * (1024 / 8) + (bid >> 3);
    const int bm  = wg >> 5;
    const int bn  = wg & 31;

    // global_load_lds decomposition: per wave-instr 64 lanes x 16B = 8 rows
    const int lrow = lane >> 3;          // 0..7 row within 8-row slab
    const int lcol = (lane & 7) * 8;     // k-elem offset (8 bf16 = 16B)

    const unsigned short* Abase = A + (size_t)(bm * 128 + wid * 32 + lrow) * KDIM + lcol;
    const unsigned short* Bbase = B + (size_t)(bn * 128 + wid * 32 + lrow) * KDIM + lcol;

    f32x4 acc[4][4];
    #pragma unroll
    for (int i = 0; i < 4; ++i)
        #pragma unroll
        for (int j = 0; j < 4; ++j)
            acc[i][j] = (f32x4)0.0f;

    for (int kt = 0; kt < KDIM / 64; ++kt) {
        // stage tile kt into LDS via async direct-to-LDS (linear layout)
        #pragma unroll
        for (int i = 0; i < 4; ++i) {
            gload_lds16(Abase + (size_t)(i * 8) * KDIM + kt * 64,
                        &As[(wid * 32 + i * 8) * 64]);
            gload_lds16(Bbase + (size_t)(i * 8) * KDIM + kt * 64,
                        &Bs[(wid * 32 + i * 8) * 64]);
        }
        __syncthreads();

        #pragma unroll
        for (int k0 = 0; k0 < 2; ++k0) {
            const int kk = k0 * 32 + (lane >> 4) * 8;
            bf16x8 af[4], bfr[4];
            #pragma unroll
            for (int mf = 0; mf < 4; ++mf)
                af[mf] = *(const bf16x8*)&As[(wm * 64 + mf * 16 + (lane & 15)) * 64 + kk];
            #pragma unroll
            for (int nf = 0; nf < 4; ++nf)
                bfr[nf] = *(const bf16x8*)&Bs[(wn * 64 + nf * 16 + (lane & 15)) * 64 + kk];
            #pragma unroll
            for (int mf = 0; mf < 4; ++mf)
                #pragma unroll
                for (int nf = 0; nf < 4; ++nf)
                    acc[mf][nf] = __builtin_amdgcn_mfma_f32_16x16x32_bf16(
                        af[mf], bfr[nf], acc[mf][nf], 0, 0, 0);
        }
        __syncthreads();
    }

    // Epilogue: bias + maxpool(4 along n) + sum + atomic row add.
    // C/D layout (16x16x32): col = lane&15, row = (lane>>4)*4 + reg.
    float rs[4][4];
    #pragma unroll
    for (int mf = 0; mf < 4; ++mf)
        #pragma unroll
        for (int r = 0; r < 4; ++r)
            rs[mf][r] = 0.0f;

    #pragma unroll
    for (int nf = 0; nf < 4; ++nf) {
        const float bv = bias[bn * 128 + wn * 64 + nf * 16 + (lane & 15)];
        #pragma unroll
        for (int mf = 0; mf < 4; ++mf) {
            #pragma unroll
            for (int r = 0; r < 4; ++r) {
                float v = acc[mf][nf][r] + bv;
                v = fmaxf(v, __shfl_xor(v, 1));
                v = fmaxf(v, __shfl_xor(v, 2));
                v += __shfl_xor(v, 4);
                v += __shfl_xor(v, 8);
                rs[mf][r] += v;
            }
        }
    }

    if ((lane & 15) == 0) {
        #pragma unroll
        for (int mf = 0; mf < 4; ++mf)
            #pragma unroll
            for (int r = 0; r < 4; ++r) {
                const int row = bm * 128 + wm * 64 + mf * 16 + (lane >> 4) * 4 + r;
                atomicAdd(&out[row], 0.5f * rs[mf][r]);
            }
    }
}

// ---------------- fallback (round-1 kernel) if d_ws too small ----------------
__global__ __launch_bounds__(256, 2)
void fused_gemm_pool_fallback(const float* __restrict__ x,
                              const float* __restrict__ W,
                              const float* __restrict__ b,
                              float* __restrict__ out)
{
    __shared__ unsigned short As[128][72];
    __shared__ unsigned short Bs[128][72];

    const int tid  = threadIdx.x;
    const int lane = tid & 63;
    const int wid  = tid >> 6;
    const int wm   = wid >> 1;
    const int wn   = wid & 1;

    const int bid = blockIdx.x;
    const int wg  = (bid & 7) * (1024 / 8) + (bid >> 3);
    const int bm  = wg >> 5;
    const int bn  = wg & 31;

    const int srow = tid >> 4;
    const int scol = tid & 15;

    const float* xbase = x + (size_t)(bm * 128 + srow) * KDIM + scol * 4;
    const float* wbase = W + (size_t)(bn * 128 + srow) * KDIM + scol * 4;

    f32x4 acc[4][4];
    #pragma unroll
    for (int i = 0; i < 4; ++i)
        #pragma unroll
        for (int j = 0; j < 4; ++j)
            acc[i][j] = (f32x4)0.0f;

    float4 ra[8], rb[8];
    #pragma unroll
    for (int p = 0; p < 8; ++p) {
        ra[p] = *(const float4*)(xbase + (size_t)(p * 16) * KDIM);
        rb[p] = *(const float4*)(wbase + (size_t)(p * 16) * KDIM);
    }

    for (int kt = 0; kt < KDIM / 64; ++kt) {
        #pragma unroll
        for (int p = 0; p < 8; ++p) {
            const int r = srow + p * 16;
            uint2 pa, pb;
            pa.x = pack_bf16x2(ra[p].x, ra[p].y);
            pa.y = pack_bf16x2(ra[p].z, ra[p].w);
            pb.x = pack_bf16x2(rb[p].x, rb[p].y);
            pb.y = pack_bf16x2(rb[p].z, rb[p].w);
            *(uint2*)&As[r][scol * 4] = pa;
            *(uint2*)&Bs[r][scol * 4] = pb;
        }
        __syncthreads();

        if (kt + 1 < KDIM / 64) {
            const float* xa = xbase + (size_t)(kt + 1) * 64;
            const float* wa = wbase + (size_t)(kt + 1) * 64;
            #pragma unroll
            for (int p = 0; p < 8; ++p) {
                ra[p] = *(const float4*)(xa + (size_t)(p * 16) * KDIM);
                rb[p] = *(const float4*)(wa + (size_t)(p * 16) * KDIM);
            }
        }

        #pragma unroll
        for (int k0 = 0; k0 < 2; ++k0) {
            const int kk = k0 * 32 + (lane >> 4) * 8;
            bf16x8 af[4], bfr[4];
            #pragma unroll
            for (int mf = 0; mf < 4; ++mf)
                af[mf] = *(const bf16x8*)&As[wm * 64 + mf * 16 + (lane & 15)][kk];
            #pragma unroll
            for (int nf = 0; nf < 4; ++nf)
                bfr[nf] = *(const bf16x8*)&Bs[wn * 64 + nf * 16 + (lane & 15)][kk];
            #pragma unroll
            for (int mf = 0; mf < 4; ++mf)
                #pragma unroll
                for (int nf = 0; nf < 4; ++nf)
                    acc[mf][nf] = __builtin_amdgcn_mfma_f32_16x16x32_bf16(
                        af[mf], bfr[nf], acc[mf][nf], 0, 0, 0);
        }
        __syncthreads();
    }

    float rs[4][4];
    #pragma unroll
    for (int mf = 0; mf < 4; ++mf)
        #pragma unroll
        for (int r = 0; r < 4; ++r)
            rs[mf][r] = 0.0f;

    #pragma unroll
    for (int nf = 0; nf < 4; ++nf) {
        const float bv = b[bn * 128 + wn * 64 + nf * 16 + (lane & 15)];
        #pragma unroll
        for (int mf = 0; mf < 4; ++mf) {
            #pragma unroll
            for (int r = 0; r < 4; ++r) {
                float v = acc[mf][nf][r] + bv;
                v = fmaxf(v, __shfl_xor(v, 1));
                v = fmaxf(v, __shfl_xor(v, 2));
                v += __shfl_xor(v, 4);
                v += __shfl_xor(v, 8);
                rs[mf][r] += v;
            }
        }
    }

    if ((lane & 15) == 0) {
        #pragma unroll
        for (int mf = 0; mf < 4; ++mf)
            #pragma unroll
            for (int r = 0; r < 4; ++r) {
                const int row = bm * 128 + wm * 64 + mf * 16 + (lane >> 4) * 4 + r;
                atomicAdd(&out[row], 0.5f * rs[mf][r]);
            }
    }
}

extern "C" void kernel_launch(void* const* d_in, const int* in_sizes, int n_in,
                              void* d_out, int out_size, void* d_ws, size_t ws_size,
                              hipStream_t stream) {
    const float* x = (const float*)d_in[0];
    const float* W = (const float*)d_in[1];
    const float* b = (const float*)d_in[2];
    float* out = (float*)d_out;

    hipMemsetAsync(out, 0, (size_t)out_size * sizeof(float), stream);

    const size_t need = (size_t)NELEM * 2 * sizeof(unsigned short); // 64 MB
    if (ws_size >= need) {
        unsigned short* xb = (unsigned short*)d_ws;
        unsigned short* wb = xb + (size_t)NELEM;
        cvt_f32_bf16<<<dim3(2048), dim3(256), 0, stream>>>(x, xb, NELEM);
        cvt_f32_bf16<<<dim3(2048), dim3(256), 0, stream>>>(W, wb, NELEM);
        gemm_bf16_pool<<<dim3(1024), dim3(256), 0, stream>>>(xb, wb, b, out);
    } else {
        fused_gemm_pool_fallback<<<dim3(1024), dim3(256), 0, stream>>>(x, W, b, out);
    }
}

// Round 3
// 187.896 us; speedup vs baseline: 1.7281x; 1.3827x over previous
//
#include <hip/hip_runtime.h>
#include <hip/hip_bf16.h>

#define KDIM 4096
#define NTILE 64                 // K-tiles of 64
#define NELEM16 (1u << 24)       // 4096*4096 elems per matrix

typedef float f32x4 __attribute__((ext_vector_type(4)));
typedef short bf16x8 __attribute__((ext_vector_type(8)));

typedef const __attribute__((address_space(1))) unsigned int g_u32;
typedef __attribute__((address_space(3))) unsigned int l_u32;

__device__ __forceinline__ void gload_lds16(const void* g, void* l) {
    __builtin_amdgcn_global_load_lds((g_u32*)g, (l_u32*)l, 16, 0, 0);
}

__device__ __forceinline__ unsigned int pack_bf16x2(float lo, float hi) {
    __hip_bfloat162 h = __float22bfloat162_rn(float2{lo, hi});
    union { __hip_bfloat162 h; unsigned int u; } c; c.h = h; return c.u;
}

// ---- pack fp32 [4096][4096] -> tiled + XOR-swizzled bf16 staging image ----
// layout: [rt(16)][kt(64)][half(2)] 16KB blocks; within: rl(128) x chunk_p(8) x 8elem
// content of (rl, cp) = source row rt*256+h*128+rl, cols kt*64 + (cp^(rl&7))*8 ..+7
__global__ __launch_bounds__(256)
void pack_swz(const float* __restrict__ in, unsigned short* __restrict__ out)
{
    const unsigned int stride = gridDim.x * blockDim.x;
    for (unsigned int i = blockIdx.x * blockDim.x + threadIdx.x; i < (1u << 21); i += stride) {
        const unsigned int cp = i & 7;
        const unsigned int rl = (i >> 3) & 127;
        const unsigned int c  = cp ^ (rl & 7);
        const unsigned int h  = (i >> 10) & 1;
        const unsigned int kt = (i >> 11) & 63;
        const unsigned int rt = i >> 17;
        const unsigned int row = rt * 256 + h * 128 + rl;
        const unsigned int col = kt * 64 + c * 8;
        const float4* s = (const float4*)(in + (size_t)row * KDIM + col);
        const float4 a = s[0], b = s[1];
        uint4 o;
        o.x = pack_bf16x2(a.x, a.y); o.y = pack_bf16x2(a.z, a.w);
        o.z = pack_bf16x2(b.x, b.y); o.w = pack_bf16x2(b.z, b.w);
        *(uint4*)(out + (size_t)i * 8) = o;
    }
}

// ---- 256x256 8-phase GEMM, fused bias + maxpool4 + rowsum*0.5 ----
// LDS elem offsets: buf*32768 + op*16384 + half*8192 + rl*64 + cp*8
#define STAGE(matBase, kt, h, bufp, opIdx)                                      \
    {                                                                           \
        const unsigned short* g_ = (matBase) + ((size_t)(kt) * 2 + (h)) * 8192; \
        const unsigned int lo_ = (bufp) * 32768 + (opIdx) * 16384 + (h) * 8192 + wid * 1024; \
        gload_lds16(g_ + stageOff,       &lds[lo_]);                            \
        gload_lds16(g_ + stageOff + 512, &lds[lo_ + 512]);                      \
    }

#define PHASE(P, MFB, NFB, STAGE_STMT, VMSTMT)                                  \
    {                                                                           \
        bf16x8 af[4][2], bfr[2][2];                                             \
        _Pragma("unroll") for (int m = 0; m < 2; ++m)                           \
          _Pragma("unroll") for (int k = 0; k < 2; ++k)                         \
            af[m][k] = *(const bf16x8*)&lds[(P) * 32768 + (((MFB) + m) >> 2) * 8192 + \
                ((((MFB) + m) & 3) * 2 + wm) * 1024 + rdBase + kcp[k]];         \
        _Pragma("unroll") for (int m = 2; m < 4; ++m)                           \
          _Pragma("unroll") for (int k = 0; k < 2; ++k)                         \
            af[m][k] = *(const bf16x8*)&lds[(P) * 32768 + (((MFB) + m) >> 2) * 8192 + \
                ((((MFB) + m) & 3) * 2 + wm) * 1024 + rdBase + kcp[k]];         \
        _Pragma("unroll") for (int n = 0; n < 2; ++n)                           \
          _Pragma("unroll") for (int k = 0; k < 2; ++k)                         \
            bfr[n][k] = *(const bf16x8*)&lds[(P) * 32768 + 16384 +              \
                (((NFB) + n) >> 1) * 8192 + ((((NFB) + n) & 1) * 4 + wn) * 1024 + rdBase + kcp[k]]; \
        STAGE_STMT;                                                             \
        __builtin_amdgcn_s_barrier();                                           \
        __builtin_amdgcn_s_setprio(1);                                          \
        _Pragma("unroll") for (int m = 0; m < 4; ++m)                           \
          _Pragma("unroll") for (int n = 0; n < 2; ++n)                         \
            _Pragma("unroll") for (int k = 0; k < 2; ++k)                       \
              acc[(MFB) + m][(NFB) + n] = __builtin_amdgcn_mfma_f32_16x16x32_bf16( \
                  af[m][k], bfr[n][k], acc[(MFB) + m][(NFB) + n], 0, 0, 0);     \
        __builtin_amdgcn_s_setprio(0);                                          \
        VMSTMT;                                                                 \
        __builtin_amdgcn_s_barrier();                                           \
    }

__global__ __launch_bounds__(512, 2)
void gemm_8phase(const unsigned short* __restrict__ A,
                 const unsigned short* __restrict__ B,
                 const float* __restrict__ bias,
                 float* __restrict__ out)
{
    __shared__ unsigned short lds[65536];   // 128 KiB: [buf2][op2][half2][8192]

    const int tid  = threadIdx.x;
    const int lane = tid & 63;
    const int wid  = tid >> 6;     // 0..7
    const int wm   = wid >> 2;     // 0..1
    const int wn   = wid & 3;      // 0..3
    const int c15  = lane & 15;
    const int q4   = lane >> 4;
    const int c7   = c15 & 7;

    // 256 blocks = 16x16 output tiles; XCD-bijective swizzle (256 % 8 == 0)
    const int bid = blockIdx.x;
    const int wg  = (bid & 7) * 32 + (bid >> 3);
    const int bm  = wg >> 4;
    const int bn  = wg & 15;

    const unsigned short* Abase = A + (size_t)bm * 64 * 2 * 8192;
    const unsigned short* Bbase = B + (size_t)bn * 64 * 2 * 8192;

    const int stageOff = wid * 1024 + lane * 8;   // elem offset within a 16KB half
    const int rdBase   = c15 * 64;
    const int kcp[2]   = { ((0 + q4) ^ c7) * 8, ((4 + q4) ^ c7) * 8 };

    f32x4 acc[8][4];
    #pragma unroll
    for (int i = 0; i < 8; ++i)
        #pragma unroll
        for (int j = 0; j < 4; ++j)
            acc[i][j] = (f32x4)0.0f;

    // prologue: tile0 all 4 halves + tile1's B-half0 and A-half1
    STAGE(Abase, 0, 0, 0, 0);
    STAGE(Abase, 0, 1, 0, 0);
    STAGE(Bbase, 0, 0, 0, 1);
    STAGE(Bbase, 0, 1, 0, 1);
    STAGE(Bbase, 1, 0, 1, 1);
    STAGE(Abase, 1, 1, 1, 0);
    asm volatile("s_waitcnt vmcnt(4)" ::: "memory");
    __builtin_amdgcn_s_barrier();

    // steady-state per tile T (buf p): quads P1:(A0,B0) P2:(A1,B0) P3:(A1,B1) P4:(A0,B1)
    // stages: P1: A0(T+1)->p^1, P2: B1(T+1)->p^1, P3: B0(T+2)->p, P4: A1(T+2)->p
    // vmcnt(4) at each tile boundary leaves exactly {B0(T+2), A1(T+2)} in flight.
    #pragma unroll 2
    for (int t = 0; t < NTILE; ++t) {
        const int p = t & 1;
        PHASE(p, 0, 0, if (t + 1 < NTILE) STAGE(Abase, t + 1, 0, p ^ 1, 0), );
        PHASE(p, 4, 0, if (t + 1 < NTILE) STAGE(Bbase, t + 1, 1, p ^ 1, 1), );
        PHASE(p, 4, 2, if (t + 2 < NTILE) STAGE(Bbase, t + 2, 0, p, 1), );
        PHASE(p, 0, 2, if (t + 2 < NTILE) STAGE(Abase, t + 2, 1, p, 0),
              if (t < NTILE - 2) { asm volatile("s_waitcnt vmcnt(4)" ::: "memory"); }
              else               { asm volatile("s_waitcnt vmcnt(0)" ::: "memory"); });
    }

    // Epilogue: bias + maxpool(4 along col) + sum + atomic row add.
    // C/D frag: col = c15, row = q4*4 + r. Wave cols: (nf*4+wn)*16 + c15.
    float rs[8][4];
    #pragma unroll
    for (int mf = 0; mf < 8; ++mf)
        #pragma unroll
        for (int r = 0; r < 4; ++r)
            rs[mf][r] = 0.0f;

    #pragma unroll
    for (int nf = 0; nf < 4; ++nf) {
        const float bv = bias[bn * 256 + (nf * 4 + wn) * 16 + c15];
        #pragma unroll
        for (int mf = 0; mf < 8; ++mf) {
            #pragma unroll
            for (int r = 0; r < 4; ++r) {
                float v = acc[mf][nf][r] + bv;
                v = fmaxf(v, __shfl_xor(v, 1));
                v = fmaxf(v, __shfl_xor(v, 2));
                v += __shfl_xor(v, 4);
                v += __shfl_xor(v, 8);
                rs[mf][r] += v;
            }
        }
    }

    if (c15 == 0) {
        #pragma unroll
        for (int mf = 0; mf < 8; ++mf)
            #pragma unroll
            for (int r = 0; r < 4; ++r) {
                const int row = bm * 256 + (mf * 2 + wm) * 16 + q4 * 4 + r;
                atomicAdd(&out[row], 0.5f * rs[mf][r]);
            }
    }
}

// ---------------- fallback (round-1 kernel, verified) if d_ws too small ----------------
__global__ __launch_bounds__(256, 2)
void fused_gemm_pool_fallback(const float* __restrict__ x,
                              const float* __restrict__ W,
                              const float* __restrict__ b,
                              float* __restrict__ out)
{
    __shared__ unsigned short As[128][72];
    __shared__ unsigned short Bs[128][72];

    const int tid  = threadIdx.x;
    const int lane = tid & 63;
    const int wid  = tid >> 6;
    const int wm   = wid >> 1;
    const int wn   = wid & 1;

    const int bid = blockIdx.x;
    const int wg  = (bid & 7) * 128 + (bid >> 3);
    const int bm  = wg >> 5;
    const int bn  = wg & 31;

    const int srow = tid >> 4;
    const int scol = tid & 15;

    const float* xbase = x + (size_t)(bm * 128 + srow) * KDIM + scol * 4;
    const float* wbase = W + (size_t)(bn * 128 + srow) * KDIM + scol * 4;

    f32x4 acc[4][4];
    #pragma unroll
    for (int i = 0; i < 4; ++i)
        #pragma unroll
        for (int j = 0; j < 4; ++j)
            acc[i][j] = (f32x4)0.0f;

    float4 ra[8], rb[8];
    #pragma unroll
    for (int p = 0; p < 8; ++p) {
        ra[p] = *(const float4*)(xbase + (size_t)(p * 16) * KDIM);
        rb[p] = *(const float4*)(wbase + (size_t)(p * 16) * KDIM);
    }

    for (int kt = 0; kt < KDIM / 64; ++kt) {
        #pragma unroll
        for (int p = 0; p < 8; ++p) {
            const int r = srow + p * 16;
            uint2 pa, pb;
            pa.x = pack_bf16x2(ra[p].x, ra[p].y);
            pa.y = pack_bf16x2(ra[p].z, ra[p].w);
            pb.x = pack_bf16x2(rb[p].x, rb[p].y);
            pb.y = pack_bf16x2(rb[p].z, rb[p].w);
            *(uint2*)&As[r][scol * 4] = pa;
            *(uint2*)&Bs[r][scol * 4] = pb;
        }
        __syncthreads();

        if (kt + 1 < KDIM / 64) {
            const float* xa = xbase + (size_t)(kt + 1) * 64;
            const float* wa = wbase + (size_t)(kt + 1) * 64;
            #pragma unroll
            for (int p = 0; p < 8; ++p) {
                ra[p] = *(const float4*)(xa + (size_t)(p * 16) * KDIM);
                rb[p] = *(const float4*)(wa + (size_t)(p * 16) * KDIM);
            }
        }

        #pragma unroll
        for (int k0 = 0; k0 < 2; ++k0) {
            const int kk = k0 * 32 + (lane >> 4) * 8;
            bf16x8 af[4], bfr[4];
            #pragma unroll
            for (int mf = 0; mf < 4; ++mf)
                af[mf] = *(const bf16x8*)&As[wm * 64 + mf * 16 + (lane & 15)][kk];
            #pragma unroll
            for (int nf = 0; nf < 4; ++nf)
                bfr[nf] = *(const bf16x8*)&Bs[wn * 64 + nf * 16 + (lane & 15)][kk];
            #pragma unroll
            for (int mf = 0; mf < 4; ++mf)
                #pragma unroll
                for (int nf = 0; nf < 4; ++nf)
                    acc[mf][nf] = __builtin_amdgcn_mfma_f32_16x16x32_bf16(
                        af[mf], bfr[nf], acc[mf][nf], 0, 0, 0);
        }
        __syncthreads();
    }

    float rs[4][4];
    #pragma unroll
    for (int mf = 0; mf < 4; ++mf)
        #pragma unroll
        for (int r = 0; r < 4; ++r)
            rs[mf][r] = 0.0f;

    #pragma unroll
    for (int nf = 0; nf < 4; ++nf) {
        const float bv = b[bn * 128 + wn * 64 + nf * 16 + (lane & 15)];
        #pragma unroll
        for (int mf = 0; mf < 4; ++mf) {
            #pragma unroll
            for (int r = 0; r < 4; ++r) {
                float v = acc[mf][nf][r] + bv;
                v = fmaxf(v, __shfl_xor(v, 1));
                v = fmaxf(v, __shfl_xor(v, 2));
                v += __shfl_xor(v, 4);
                v += __shfl_xor(v, 8);
                rs[mf][r] += v;
            }
        }
    }

    if ((lane & 15) == 0) {
        #pragma unroll
        for (int mf = 0; mf < 4; ++mf)
            #pragma unroll
            for (int r = 0; r < 4; ++r) {
                const int row = bm * 128 + wm * 64 + mf * 16 + (lane >> 4) * 4 + r;
                atomicAdd(&out[row], 0.5f * rs[mf][r]);
            }
    }
}

extern "C" void kernel_launch(void* const* d_in, const int* in_sizes, int n_in,
                              void* d_out, int out_size, void* d_ws, size_t ws_size,
                              hipStream_t stream) {
    const float* x = (const float*)d_in[0];
    const float* W = (const float*)d_in[1];
    const float* b = (const float*)d_in[2];
    float* out = (float*)d_out;

    hipMemsetAsync(out, 0, (size_t)out_size * sizeof(float), stream);

    const size_t need = (size_t)NELEM16 * 2 * sizeof(unsigned short); // 64 MB
    if (ws_size >= need) {
        unsigned short* xb = (unsigned short*)d_ws;
        unsigned short* wb = xb + (size_t)NELEM16;
        pack_swz<<<dim3(2048), dim3(256), 0, stream>>>(x, xb);
        pack_swz<<<dim3(2048), dim3(256), 0, stream>>>(W, wb);
        gemm_8phase<<<dim3(256), dim3(512), 0, stream>>>(xb, wb, b, out);
    } else {
        fused_gemm_pool_fallback<<<dim3(1024), dim3(256), 0, stream>>>(x, W, b, out);
    }
}

// Round 4
// 170.908 us; speedup vs baseline: 1.8999x; 1.0994x over previous
//
#include <hip/hip_runtime.h>
#include <hip/hip_bf16.h>

#define KDIM 4096
#define NTILE 64                 // K-tiles of 64
#define NELEM16 (1u << 24)       // 4096*4096 elems per matrix

typedef float f32x4 __attribute__((ext_vector_type(4)));
typedef short bf16x8 __attribute__((ext_vector_type(8)));

typedef const __attribute__((address_space(1))) unsigned int g_u32;
typedef __attribute__((address_space(3))) unsigned int l_u32;

__device__ __forceinline__ void gload_lds16(const void* g, void* l) {
    __builtin_amdgcn_global_load_lds((g_u32*)g, (l_u32*)l, 16, 0, 0);
}

__device__ __forceinline__ unsigned int pack_bf16x2(float lo, float hi) {
    __hip_bfloat162 h = __float22bfloat162_rn(float2{lo, hi});
    union { __hip_bfloat162 h; unsigned int u; } c; c.h = h; return c.u;
}

// ---- pack fp32 [4096][4096] -> tiled + XOR-swizzled bf16 staging image ----
// layout: [rt(16)][kt(64)][half(2)] 16KB blocks; within: rl(128) x chunk_p(8) x 8elem
// content of (rl, cp) = source row rt*256+h*128+rl, cols kt*64 + (cp^(rl&7))*8 ..+7
__global__ __launch_bounds__(256)
void pack_swz2(const float* __restrict__ x, const float* __restrict__ W,
               unsigned short* __restrict__ xb, unsigned short* __restrict__ wb)
{
    const unsigned int stride = gridDim.x * blockDim.x;
    for (unsigned int i = blockIdx.x * blockDim.x + threadIdx.x; i < (1u << 22); i += stride) {
        const unsigned int j  = i & ((1u << 21) - 1);
        const float* __restrict__ in = (i >> 21) ? W : x;
        unsigned short* __restrict__ out = (i >> 21) ? wb : xb;
        const unsigned int cp = j & 7;
        const unsigned int rl = (j >> 3) & 127;
        const unsigned int c  = cp ^ (rl & 7);
        const unsigned int h  = (j >> 10) & 1;
        const unsigned int kt = (j >> 11) & 63;
        const unsigned int rt = j >> 17;
        const unsigned int row = rt * 256 + h * 128 + rl;
        const unsigned int col = kt * 64 + c * 8;
        const float4* s = (const float4*)(in + (size_t)row * KDIM + col);
        const float4 a = s[0], b = s[1];
        uint4 o;
        o.x = pack_bf16x2(a.x, a.y); o.y = pack_bf16x2(a.z, a.w);
        o.z = pack_bf16x2(b.x, b.y); o.w = pack_bf16x2(b.z, b.w);
        *(uint4*)(out + (size_t)j * 8) = o;
    }
}

// ---- 256x256 8-phase GEMM, fused bias + maxpool4 + rowsum*0.5 ----
// LDS elem offsets: buf*32768 + op*16384 + half*8192 + rowfrag*1024 + c15*64 + swzchunk*8
#define STAGE(matBase, kt, h, bufp, opIdx)                                      \
    {                                                                           \
        const unsigned short* g_ = (matBase) + ((size_t)(kt) * 2 + (h)) * 8192; \
        const unsigned int lo_ = (bufp) * 32768 + (opIdx) * 16384 + (h) * 8192 + wid * 1024; \
        gload_lds16(g_ + stageOff,       &lds[lo_]);                            \
        gload_lds16(g_ + stageOff + 512, &lds[lo_ + 512]);                      \
    }

__global__ __launch_bounds__(512, 2)
void gemm_8phase(const unsigned short* __restrict__ A,
                 const unsigned short* __restrict__ B,
                 const float* __restrict__ bias,
                 float* __restrict__ out)
{
    __shared__ unsigned short lds[65536];   // 128 KiB: [buf2][op2][half2][8192]

    const int tid  = threadIdx.x;
    const int lane = tid & 63;
    const int wid  = tid >> 6;     // 0..7
    const int wm   = wid >> 2;     // 0..1
    const int wn   = wid & 3;      // 0..3
    const int c15  = lane & 15;
    const int q4   = lane >> 4;
    const int c7   = c15 & 7;

    // 256 blocks = 16x16 output tiles; XCD-bijective swizzle (256 % 8 == 0)
    const int bid = blockIdx.x;
    const int wg  = (bid & 7) * 32 + (bid >> 3);
    const int bm  = wg >> 4;
    const int bn  = wg & 15;

    const unsigned short* Abase = A + (size_t)bm * 64 * 2 * 8192;
    const unsigned short* Bbase = B + (size_t)bn * 64 * 2 * 8192;

    const int stageOff = wid * 1024 + lane * 8;   // elem offset within a 16KB half
    const int rdBase   = c15 * 64;
    const int kcp[2]   = { ((0 + q4) ^ c7) * 8, ((4 + q4) ^ c7) * 8 };

    f32x4 acc[8][4];
    #pragma unroll
    for (int i = 0; i < 8; ++i)
        #pragma unroll
        for (int j = 0; j < 4; ++j)
            acc[i][j] = (f32x4)0.0f;

    bf16x8 afr[4][2];    // current A-half fragments (reused across 2 phases)
    bf16x8 b0f[2][2];    // B-half0 fragments (live whole tile)
    bf16x8 b1f[2][2];    // B-half1 fragments (live P2..P3)

    // prologue: tile0 all 4 halves -> buf0, then tile1's B-half0 / A-half1 -> buf1
    STAGE(Abase, 0, 0, 0, 0);
    STAGE(Abase, 0, 1, 0, 0);
    STAGE(Bbase, 0, 0, 0, 1);
    STAGE(Bbase, 0, 1, 0, 1);
    STAGE(Bbase, 1, 0, 1, 1);
    STAGE(Abase, 1, 1, 1, 0);
    asm volatile("s_waitcnt vmcnt(4)" ::: "memory");
    __builtin_amdgcn_s_barrier();

    // per tile T (buf p) quadrant order: P1:(A0,B0) P2:(A0,B1) P3:(A1,B1) P4:(A1,B0)
    // LDS reads: P1: A0+B0 (12), P2: B1 (4), P3: A1 (8), P4: none  -> 24/tile (minimal)
    // stages: P1: A0(T+1)->p^1, P2: B1(T+1)->p^1, P3: B0(T+2)->p, P4: A1(T+2)->p
    // vmcnt(4) at tile end leaves exactly {B0(T+2), A1(T+2)} in flight.
    #pragma unroll 2
    for (int t = 0; t < NTILE; ++t) {
        const int p  = t & 1;
        const int pb = p * 32768;

        // ---- P1: quad (A-half0, B-half0) ----
        #pragma unroll
        for (int m = 0; m < 4; ++m)
            #pragma unroll
            for (int k = 0; k < 2; ++k)
                afr[m][k] = *(const bf16x8*)&lds[pb + (m * 2 + wm) * 1024 + rdBase + kcp[k]];
        #pragma unroll
        for (int n = 0; n < 2; ++n)
            #pragma unroll
            for (int k = 0; k < 2; ++k)
                b0f[n][k] = *(const bf16x8*)&lds[pb + 16384 + (n * 4 + wn) * 1024 + rdBase + kcp[k]];
        if (t + 1 < NTILE) STAGE(Abase, t + 1, 0, p ^ 1, 0);
        __builtin_amdgcn_s_barrier();
        __builtin_amdgcn_s_setprio(1);
        #pragma unroll
        for (int m = 0; m < 4; ++m)
            #pragma unroll
            for (int n = 0; n < 2; ++n)
                #pragma unroll
                for (int k = 0; k < 2; ++k)
                    acc[m][n] = __builtin_amdgcn_mfma_f32_16x16x32_bf16(
                        afr[m][k], b0f[n][k], acc[m][n], 0, 0, 0);
        __builtin_amdgcn_s_setprio(0);
        __builtin_amdgcn_s_barrier();

        // ---- P2: quad (A-half0, B-half1) ----
        #pragma unroll
        for (int n = 0; n < 2; ++n)
            #pragma unroll
            for (int k = 0; k < 2; ++k)
                b1f[n][k] = *(const bf16x8*)&lds[pb + 16384 + 8192 + (n * 4 + wn) * 1024 + rdBase + kcp[k]];
        if (t + 1 < NTILE) STAGE(Bbase, t + 1, 1, p ^ 1, 1);
        __builtin_amdgcn_s_barrier();
        __builtin_amdgcn_s_setprio(1);
        #pragma unroll
        for (int m = 0; m < 4; ++m)
            #pragma unroll
            for (int n = 0; n < 2; ++n)
                #pragma unroll
                for (int k = 0; k < 2; ++k)
                    acc[m][2 + n] = __builtin_amdgcn_mfma_f32_16x16x32_bf16(
                        afr[m][k], b1f[n][k], acc[m][2 + n], 0, 0, 0);
        __builtin_amdgcn_s_setprio(0);
        __builtin_amdgcn_s_barrier();

        // ---- P3: quad (A-half1, B-half1) ----
        #pragma unroll
        for (int m = 0; m < 4; ++m)
            #pragma unroll
            for (int k = 0; k < 2; ++k)
                afr[m][k] = *(const bf16x8*)&lds[pb + 8192 + (m * 2 + wm) * 1024 + rdBase + kcp[k]];
        if (t + 2 < NTILE) STAGE(Bbase, t + 2, 0, p, 1);
        __builtin_amdgcn_s_barrier();
        __builtin_amdgcn_s_setprio(1);
        #pragma unroll
        for (int m = 0; m < 4; ++m)
            #pragma unroll
            for (int n = 0; n < 2; ++n)
                #pragma unroll
                for (int k = 0; k < 2; ++k)
                    acc[4 + m][2 + n] = __builtin_amdgcn_mfma_f32_16x16x32_bf16(
                        afr[m][k], b1f[n][k], acc[4 + m][2 + n], 0, 0, 0);
        __builtin_amdgcn_s_setprio(0);
        __builtin_amdgcn_s_barrier();

        // ---- P4: quad (A-half1, B-half0) — no LDS reads ----
        if (t + 2 < NTILE) STAGE(Abase, t + 2, 1, p, 0);
        __builtin_amdgcn_s_barrier();
        __builtin_amdgcn_s_setprio(1);
        #pragma unroll
        for (int m = 0; m < 4; ++m)
            #pragma unroll
            for (int n = 0; n < 2; ++n)
                #pragma unroll
                for (int k = 0; k < 2; ++k)
                    acc[4 + m][n] = __builtin_amdgcn_mfma_f32_16x16x32_bf16(
                        afr[m][k], b0f[n][k], acc[4 + m][n], 0, 0, 0);
        __builtin_amdgcn_s_setprio(0);
        if (t < NTILE - 2) { asm volatile("s_waitcnt vmcnt(4)" ::: "memory"); }
        else               { asm volatile("s_waitcnt vmcnt(0)" ::: "memory"); }
        __builtin_amdgcn_s_barrier();
    }

    // Epilogue: bias + maxpool(4 along col) + sum + atomic row add.
    // C/D frag: col = c15, row = q4*4 + r. Wave cols: (nf*4+wn)*16 + c15.
    float rs[8][4];
    #pragma unroll
    for (int mf = 0; mf < 8; ++mf)
        #pragma unroll
        for (int r = 0; r < 4; ++r)
            rs[mf][r] = 0.0f;

    #pragma unroll
    for (int nf = 0; nf < 4; ++nf) {
        const float bv = bias[bn * 256 + (nf * 4 + wn) * 16 + c15];
        #pragma unroll
        for (int mf = 0; mf < 8; ++mf) {
            #pragma unroll
            for (int r = 0; r < 4; ++r) {
                float v = acc[mf][nf][r] + bv;
                v = fmaxf(v, __shfl_xor(v, 1));
                v = fmaxf(v, __shfl_xor(v, 2));
                v += __shfl_xor(v, 4);
                v += __shfl_xor(v, 8);
                rs[mf][r] += v;
            }
        }
    }

    if (c15 == 0) {
        #pragma unroll
        for (int mf = 0; mf < 8; ++mf)
            #pragma unroll
            for (int r = 0; r < 4; ++r) {
                const int row = bm * 256 + (mf * 2 + wm) * 16 + q4 * 4 + r;
                atomicAdd(&out[row], 0.5f * rs[mf][r]);
            }
    }
}

// ---------------- fallback (round-1 kernel, verified) if d_ws too small ----------------
__global__ __launch_bounds__(256, 2)
void fused_gemm_pool_fallback(const float* __restrict__ x,
                              const float* __restrict__ W,
                              const float* __restrict__ b,
                              float* __restrict__ out)
{
    __shared__ unsigned short As[128][72];
    __shared__ unsigned short Bs[128][72];

    const int tid  = threadIdx.x;
    const int lane = tid & 63;
    const int wid  = tid >> 6;
    const int wm   = wid >> 1;
    const int wn   = wid & 1;

    const int bid = blockIdx.x;
    const int wg  = (bid & 7) * 128 + (bid >> 3);
    const int bm  = wg >> 5;
    const int bn  = wg & 31;

    const int srow = tid >> 4;
    const int scol = tid & 15;

    const float* xbase = x + (size_t)(bm * 128 + srow) * KDIM + scol * 4;
    const float* wbase = W + (size_t)(bn * 128 + srow) * KDIM + scol * 4;

    f32x4 acc[4][4];
    #pragma unroll
    for (int i = 0; i < 4; ++i)
        #pragma unroll
        for (int j = 0; j < 4; ++j)
            acc[i][j] = (f32x4)0.0f;

    float4 ra[8], rb[8];
    #pragma unroll
    for (int p = 0; p < 8; ++p) {
        ra[p] = *(const float4*)(xbase + (size_t)(p * 16) * KDIM);
        rb[p] = *(const float4*)(wbase + (size_t)(p * 16) * KDIM);
    }

    for (int kt = 0; kt < KDIM / 64; ++kt) {
        #pragma unroll
        for (int p = 0; p < 8; ++p) {
            const int r = srow + p * 16;
            uint2 pa, pb;
            pa.x = pack_bf16x2(ra[p].x, ra[p].y);
            pa.y = pack_bf16x2(ra[p].z, ra[p].w);
            pb.x = pack_bf16x2(rb[p].x, rb[p].y);
            pb.y = pack_bf16x2(rb[p].z, rb[p].w);
            *(uint2*)&As[r][scol * 4] = pa;
            *(uint2*)&Bs[r][scol * 4] = pb;
        }
        __syncthreads();

        if (kt + 1 < KDIM / 64) {
            const float* xa = xbase + (size_t)(kt + 1) * 64;
            const float* wa = wbase + (size_t)(kt + 1) * 64;
            #pragma unroll
            for (int p = 0; p < 8; ++p) {
                ra[p] = *(const float4*)(xa + (size_t)(p * 16) * KDIM);
                rb[p] = *(const float4*)(wa + (size_t)(p * 16) * KDIM);
            }
        }

        #pragma unroll
        for (int k0 = 0; k0 < 2; ++k0) {
            const int kk = k0 * 32 + (lane >> 4) * 8;
            bf16x8 af[4], bfr[4];
            #pragma unroll
            for (int mf = 0; mf < 4; ++mf)
                af[mf] = *(const bf16x8*)&As[wm * 64 + mf * 16 + (lane & 15)][kk];
            #pragma unroll
            for (int nf = 0; nf < 4; ++nf)
                bfr[nf] = *(const bf16x8*)&Bs[wn * 64 + nf * 16 + (lane & 15)][kk];
            #pragma unroll
            for (int mf = 0; mf < 4; ++mf)
                #pragma unroll
                for (int nf = 0; nf < 4; ++nf)
                    acc[mf][nf] = __builtin_amdgcn_mfma_f32_16x16x32_bf16(
                        af[mf], bfr[nf], acc[mf][nf], 0, 0, 0);
        }
        __syncthreads();
    }

    float rs[4][4];
    #pragma unroll
    for (int mf = 0; mf < 4; ++mf)
        #pragma unroll
        for (int r = 0; r < 4; ++r)
            rs[mf][r] = 0.0f;

    #pragma unroll
    for (int nf = 0; nf < 4; ++nf) {
        const float bv = b[bn * 128 + wn * 64 + nf * 16 + (lane & 15)];
        #pragma unroll
        for (int mf = 0; mf < 4; ++mf) {
            #pragma unroll
            for (int r = 0; r < 4; ++r) {
                float v = acc[mf][nf][r] + bv;
                v = fmaxf(v, __shfl_xor(v, 1));
                v = fmaxf(v, __shfl_xor(v, 2));
                v += __shfl_xor(v, 4);
                v += __shfl_xor(v, 8);
                rs[mf][r] += v;
            }
        }
    }

    if ((lane & 15) == 0) {
        #pragma unroll
        for (int mf = 0; mf < 4; ++mf)
            #pragma unroll
            for (int r = 0; r < 4; ++r) {
                const int row = bm * 128 + wm * 64 + mf * 16 + (lane >> 4) * 4 + r;
                atomicAdd(&out[row], 0.5f * rs[mf][r]);
            }
    }
}

extern "C" void kernel_launch(void* const* d_in, const int* in_sizes, int n_in,
                              void* d_out, int out_size, void* d_ws, size_t ws_size,
                              hipStream_t stream) {
    const float* x = (const float*)d_in[0];
    const float* W = (const float*)d_in[1];
    const float* b = (const float*)d_in[2];
    float* out = (float*)d_out;

    hipMemsetAsync(out, 0, (size_t)out_size * sizeof(float), stream);

    const size_t need = (size_t)NELEM16 * 2 * sizeof(unsigned short); // 64 MB
    if (ws_size >= need) {
        unsigned short* xb = (unsigned short*)d_ws;
        unsigned short* wb = xb + (size_t)NELEM16;
        pack_swz2<<<dim3(2048), dim3(256), 0, stream>>>(x, W, xb, wb);
        gemm_8phase<<<dim3(256), dim3(512), 0, stream>>>(xb, wb, b, out);
    } else {
        fused_gemm_pool_fallback<<<dim3(1024), dim3(256), 0, stream>>>(x, W, b, out);
    }
}